// Round 6
// baseline (201.629 us; speedup 1.0000x reference)
//
#include <hip/hip_runtime.h>

#define BOX   256
#define KS    9
#define HALF  4
#define NPTS  20000
#define NB    16
#define NLAT  8
#define CANW  264                 // BOX + 2*HALF
#define NBLK  1250                // point blocks: 1250 * 4 waves * 64 pts = 320000
#define NCONV 128                 // last-128 tickets run the conv (2 stripes each)
#define CANVAS_ELEMS (NB * CANW * CANW)

typedef _Float16 half8   __attribute__((ext_vector_type(8)));
typedef float    floatx4 __attribute__((ext_vector_type(4)));

// d_ws layout: [0,16) counter (int, zeroed by memset) ; [16, ...) canvas fp32
#define CANVAS_BYTE_OFF 16

// LDS: point phase uses [0,17712); conv phase reuses all of it:
//   C[24*264] fp32 = 25344 B,  T[24*256] fp32 = 24576 B  -> 49920 B
#define SM_BYTES 49920

__device__ __forceinline__ int perm_inv(int k) {
    return ((k >> 2) & 1) * 16 + (k >> 3) * 4 + (k & 3);
}

__global__ __launch_bounds__(256, 2) void mega_kernel(
    const float* __restrict__ z, const float* __restrict__ r,
    const float* __restrict__ pos, const float* __restrict__ amp,
    const float* __restrict__ linamp1_W, const float* __restrict__ ampblock_W,
    const float* __restrict__ ampblock_b, const float* __restrict__ linamp2_W,
    const float* __restrict__ linamp2_b, const float* __restrict__ lin0_W,
    const float* __restrict__ deform_W, const float* __restrict__ deform_b,
    const float* __restrict__ lin1a_W, const float* __restrict__ lin1b_W,
    const float* __restrict__ k2, const int* __restrict__ dflag,
    int* __restrict__ counter, float* __restrict__ canvas,
    float* __restrict__ img, float* __restrict__ pos_def_out,
    float* __restrict__ res_out, float* __restrict__ amp_corr_out)
{
    __shared__ __align__(16) char smem[SM_BYTES];
    __shared__ int s_tk;
    _Float16* wh       = (_Float16*)smem;
    float*    linamp2p = (float*)(smem + 16384);
    float*    lin1ap   = (float*)(smem + 16512);
    float*    ampb     = (float*)(smem + 16896);
    float*    defb     = (float*)(smem + 17280);

    // ---------------- phase A: block-local LDS weight build ----------------
    for (int e = threadIdx.x; e < 8192; e += 256) {
        const int mat = e >> 10, rem = e & 1023, m = rem >> 5, k = rem & 31;
        float v = 0.f;
        if (mat == 0)      { if (k < 4)  v = linamp1_W[m * 4 + k]; }
        else if (mat <= 3) { v = ampblock_W[(mat - 1) * 1024 + m * 32 + perm_inv(k)]; }
        else if (mat == 4) { if (k < 10) v = lin0_W[m * 10 + k]; }
        else               { v = deform_W[(mat - 5) * 1024 + m * 32 + perm_inv(k)]; }
        wh[e] = (_Float16)v;
    }
    if (threadIdx.x < 32) linamp2p[threadIdx.x] = linamp2_W[perm_inv(threadIdx.x)];
    if (threadIdx.x < 96) {
        lin1ap[threadIdx.x] = lin1a_W[(threadIdx.x >> 5) * 32 + perm_inv(threadIdx.x & 31)];
        ampb[threadIdx.x]   = ampblock_b[threadIdx.x];
        defb[threadIdx.x]   = deform_b[threadIdx.x];
    }
    __syncthreads();

    // ---------------- phase B: points (4 groups of 16 per wave) ----------------
    const int lane = threadIdx.x & 63;
    const int n    = lane & 15;
    const int quad = lane >> 4;
    const int aoff = quad * 8;
    const int s    = blockIdx.x * 4 + (threadIdx.x >> 6);   // set id, 0..4999
    const int d    = *dflag;
    const float ampv = amp[0];
    const float l2b  = linamp2_b[0];
    const floatx4 zero = {0.f, 0.f, 0.f, 0.f};

    {
        int   bb[4];
        float px[4], py[4], pz[4];
        half8 bfa[4], bfd[4];
        #pragma unroll
        for (int g = 0; g < 4; ++g) {
            const int base_bp = s * 64 + g * 16;
            const int b = base_bp / NPTS;        // groups of 16 never cross batch
            const int p = base_bp - b * NPTS + n;
            bb[g] = b;
            px[g] = pos[3 * p + 0];
            py[g] = pos[3 * p + 1];
            pz[g] = pos[3 * p + 2];
            float zl[NLAT];
            #pragma unroll
            for (int k = 0; k < NLAT; ++k) zl[k] = z[b * NLAT + k];
            half8 t;
            #pragma unroll
            for (int j = 0; j < 8; ++j) t[j] = (_Float16)0.f;
            bfa[g] = t; bfd[g] = t;
            if (quad == 0) {
                bfa[g][0] = (_Float16)px[g]; bfa[g][1] = (_Float16)py[g];
                bfa[g][2] = (_Float16)pz[g]; bfa[g][3] = (_Float16)zl[7];
                bfd[g][0] = (_Float16)px[g]; bfd[g][1] = (_Float16)py[g];
                bfd[g][2] = (_Float16)pz[g]; bfd[g][3] = (_Float16)zl[0];
                bfd[g][4] = (_Float16)zl[1]; bfd[g][5] = (_Float16)zl[2];
                bfd[g][6] = (_Float16)zl[3]; bfd[g][7] = (_Float16)zl[4];
            } else if (quad == 1) {
                bfd[g][0] = (_Float16)zl[5]; bfd[g][1] = (_Float16)zl[6];
            }
        }

        // ---- amplitude head ----
        float xB[4][8];
        {
            half8 a0 = *(const half8*)(wh + n * 32 + aoff);
            half8 a1 = *(const half8*)(wh + (n + 16) * 32 + aoff);
            #pragma unroll
            for (int g = 0; g < 4; ++g) {
                floatx4 c0 = __builtin_amdgcn_mfma_f32_16x16x32_f16(a0, bfa[g], zero, 0, 0, 0);
                floatx4 c1 = __builtin_amdgcn_mfma_f32_16x16x32_f16(a1, bfa[g], zero, 0, 0, 0);
                #pragma unroll
                for (int rr = 0; rr < 4; ++rr) { xB[g][rr] = c0[rr]; xB[g][4 + rr] = c1[rr]; }
            }
        }
        #pragma unroll
        for (int l = 0; l < 3; ++l) {
            const _Float16* M = wh + (1 + l) * 1024;
            half8 a0 = *(const half8*)(M + n * 32 + aoff);
            half8 a1 = *(const half8*)(M + (n + 16) * 32 + aoff);
            floatx4 b0 = *(const floatx4*)(ampb + l * 32 + quad * 4);
            floatx4 b1 = *(const floatx4*)(ampb + l * 32 + 16 + quad * 4);
            #pragma unroll
            for (int g = 0; g < 4; ++g) {
                half8 hf;
                #pragma unroll
                for (int j = 0; j < 8; ++j) hf[j] = (_Float16)xB[g][j];
                floatx4 d0 = __builtin_amdgcn_mfma_f32_16x16x32_f16(a0, hf, zero, 0, 0, 0);
                floatx4 d1 = __builtin_amdgcn_mfma_f32_16x16x32_f16(a1, hf, zero, 0, 0, 0);
                #pragma unroll
                for (int rr = 0; rr < 4; ++rr) {
                    xB[g][rr]     += fmaxf(d0[rr] + b0[rr], 0.f);
                    xB[g][4 + rr] += fmaxf(d1[rr] + b1[rr], 0.f);
                }
            }
        }
        float corr[4];
        {
            floatx4 wa = *(const floatx4*)(linamp2p + aoff);
            floatx4 wb = *(const floatx4*)(linamp2p + aoff + 4);
            #pragma unroll
            for (int g = 0; g < 4; ++g) {
                float sd = 0.f;
                #pragma unroll
                for (int rr = 0; rr < 4; ++rr) sd += wa[rr] * xB[g][rr] + wb[rr] * xB[g][4 + rr];
                sd += __shfl_xor(sd, 16);
                sd += __shfl_xor(sd, 32);
                corr[g] = 1.f / (1.f + __expf(-(sd + l2b)));
            }
        }

        // ---- deformation head ----
        float r0[4] = {0.f,0.f,0.f,0.f}, r1[4] = {0.f,0.f,0.f,0.f}, r2[4] = {0.f,0.f,0.f,0.f};
        if (d > 0) {
            {
                const _Float16* M = wh + 4 * 1024;
                half8 a0 = *(const half8*)(M + n * 32 + aoff);
                half8 a1 = *(const half8*)(M + (n + 16) * 32 + aoff);
                #pragma unroll
                for (int g = 0; g < 4; ++g) {
                    floatx4 c0 = __builtin_amdgcn_mfma_f32_16x16x32_f16(a0, bfd[g], zero, 0, 0, 0);
                    floatx4 c1 = __builtin_amdgcn_mfma_f32_16x16x32_f16(a1, bfd[g], zero, 0, 0, 0);
                    #pragma unroll
                    for (int rr = 0; rr < 4; ++rr) { xB[g][rr] = c0[rr]; xB[g][4 + rr] = c1[rr]; }
                }
            }
            #pragma unroll
            for (int l = 0; l < 3; ++l) {
                const _Float16* M = wh + (5 + l) * 1024;
                half8 a0 = *(const half8*)(M + n * 32 + aoff);
                half8 a1 = *(const half8*)(M + (n + 16) * 32 + aoff);
                floatx4 b0 = *(const floatx4*)(defb + l * 32 + quad * 4);
                floatx4 b1 = *(const floatx4*)(defb + l * 32 + 16 + quad * 4);
                #pragma unroll
                for (int g = 0; g < 4; ++g) {
                    half8 hf;
                    #pragma unroll
                    for (int j = 0; j < 8; ++j) hf[j] = (_Float16)xB[g][j];
                    floatx4 d0 = __builtin_amdgcn_mfma_f32_16x16x32_f16(a0, hf, zero, 0, 0, 0);
                    floatx4 d1 = __builtin_amdgcn_mfma_f32_16x16x32_f16(a1, hf, zero, 0, 0, 0);
                    #pragma unroll
                    for (int rr = 0; rr < 4; ++rr) {
                        xB[g][rr]     += fmaxf(d0[rr] + b0[rr], 0.f);
                        xB[g][4 + rr] += fmaxf(d1[rr] + b1[rr], 0.f);
                    }
                }
            }
            #pragma unroll
            for (int g = 0; g < 4; ++g) {
                float t3[3];
                #pragma unroll
                for (int i = 0; i < 3; ++i) {
                    floatx4 wa = *(const floatx4*)(lin1ap + i * 32 + aoff);
                    floatx4 wb = *(const floatx4*)(lin1ap + i * 32 + aoff + 4);
                    float sd = 0.f;
                    #pragma unroll
                    for (int rr = 0; rr < 4; ++rr) sd += wa[rr] * xB[g][rr] + wb[rr] * xB[g][4 + rr];
                    sd += __shfl_xor(sd, 16);
                    sd += __shfl_xor(sd, 32);
                    t3[i] = 1.f - 2.f / (__expf(2.f * sd) + 1.f);
                }
                r0[g] = t3[0] * lin1b_W[0] + t3[1] * lin1b_W[1] + t3[2] * lin1b_W[2];
                r1[g] = t3[0] * lin1b_W[3] + t3[1] * lin1b_W[4] + t3[2] * lin1b_W[5];
                r2[g] = t3[0] * lin1b_W[6] + t3[1] * lin1b_W[7] + t3[2] * lin1b_W[8];
            }
        }

        // ---- outputs (quad-split; all quads hold full results) ----
        #pragma unroll
        for (int g = 0; g < 4; ++g) {
            const int bp = s * 64 + g * 16 + n;
            const float pdx = px[g] + r0[g], pdy = py[g] + r1[g], pdz = pz[g] + r2[g];
            if (quad == 0) {
                pos_def_out[3 * bp + 0] = pdx;
                pos_def_out[3 * bp + 1] = pdy;
                pos_def_out[3 * bp + 2] = pdz;
            } else if (quad == 1) {
                res_out[3 * bp + 0] = r0[g];
                res_out[3 * bp + 1] = r1[g];
                res_out[3 * bp + 2] = r2[g];
            } else if (quad == 2) {
                amp_corr_out[bp] = corr[g];
            } else {
                const float* rb = r + bb[g] * 9;
                const float pjx = rb[0] * pdx + rb[1] * pdy + rb[2] * pdz;
                const float pjy = rb[3] * pdx + rb[4] * pdy + rb[5] * pdz;
                const int cx = (int)rintf((pjx + 0.5f) * (float)(BOX - 1));
                const int cy = (int)rintf((pjy + 0.5f) * (float)(BOX - 1));
                if (cx >= -HALF && cx <= BOX - 1 + HALF &&
                    cy >= -HALF && cy <= BOX - 1 + HALF) {
                    atomicAdd(canvas + ((size_t)bb[g] * CANW + (cy + HALF)) * CANW + (cx + HALF),
                              ampv * corr[g]);
                }
            }
        }
    }

    // ---------------- finish ticket ----------------
    __syncthreads();   // drains every thread's atomics (vmcnt(0) before barrier)
    if (threadIdx.x == 0) {
        s_tk = __hip_atomic_fetch_add(counter, 1, __ATOMIC_ACQ_REL,
                                      __HIP_MEMORY_SCOPE_AGENT);
    }
    __syncthreads();
    const int tk = s_tk;
    if (tk < NBLK - NCONV) return;   // not a conv block

    if (threadIdx.x == 0) {
        while (__hip_atomic_load(counter, __ATOMIC_ACQUIRE,
                                 __HIP_MEMORY_SCOPE_AGENT) < NBLK) {
            __builtin_amdgcn_s_sleep(2);
        }
    }
    __syncthreads();

    // ---------------- phase C: separable conv (2 stripes per conv block) ------
    float g9[KS];
    #pragma unroll
    for (int i = 0; i < KS; ++i) {
        float sg = 0.f;
        #pragma unroll
        for (int j = 0; j < KS; ++j) sg += k2[i * KS + j];
        g9[i] = sg;
    }

    float* Cf = (float*)smem;            // [24*264]
    float* Tf = Cf + 24 * CANW;          // [24*256]
    const int x = threadIdx.x;

    for (int sp = 0; sp < 2; ++sp) {
        const int sidx = (tk - (NBLK - NCONV)) * 2 + sp;   // 0..255
        const int b  = sidx >> 4;
        const int y0 = (sidx & 15) * 16;
        const float* cb = canvas + (size_t)b * CANW * CANW + (size_t)y0 * CANW;

        // coherent load (bypass possibly-stale per-XCD L2) of 24 halo rows
        for (int i = threadIdx.x; i < 24 * CANW; i += 256)
            Cf[i] = __hip_atomic_load(cb + i, __ATOMIC_RELAXED,
                                      __HIP_MEMORY_SCOPE_AGENT);
        __syncthreads();

        #pragma unroll 4
        for (int rr = 0; rr < 24; ++rr) {
            float sacc = 0.f;
            #pragma unroll
            for (int i = 0; i < KS; ++i)
                sacc = fmaf(g9[i], Cf[rr * CANW + x + (KS - 1) - i], sacc);
            Tf[rr * 256 + x] = sacc;
        }
        __syncthreads();

        float* ib = img + ((size_t)b * BOX + y0) * BOX;
        #pragma unroll 4
        for (int yy = 0; yy < 16; ++yy) {
            float sacc = 0.f;
            #pragma unroll
            for (int i = 0; i < KS; ++i)
                sacc = fmaf(g9[i], Tf[(yy + (KS - 1) - i) * 256 + x], sacc);
            ib[yy * BOX + x] = sacc;
        }
        __syncthreads();   // before Cf/Tf reuse in next stripe
    }
}

extern "C" void kernel_launch(void* const* d_in, const int* in_sizes, int n_in,
                              void* d_out, int out_size, void* d_ws, size_t ws_size,
                              hipStream_t stream) {
    const float* z          = (const float*)d_in[0];
    const float* r          = (const float*)d_in[1];
    const float* pos        = (const float*)d_in[2];
    const float* amp        = (const float*)d_in[3];
    const float* linamp1_W  = (const float*)d_in[4];
    const float* ampblock_W = (const float*)d_in[5];
    const float* ampblock_b = (const float*)d_in[6];
    const float* linamp2_W  = (const float*)d_in[7];
    const float* linamp2_b  = (const float*)d_in[8];
    const float* lin0_W     = (const float*)d_in[9];
    const float* deform_W   = (const float*)d_in[10];
    const float* deform_b   = (const float*)d_in[11];
    const float* lin1a_W    = (const float*)d_in[12];
    const float* lin1b_W    = (const float*)d_in[13];
    const float* k2         = (const float*)d_in[14];
    const int*   dflag      = (const int*)d_in[15];

    float* out = (float*)d_out;
    float* img          = out;                               // [16,256,256]
    float* pos_def_out  = out + (size_t)NB * BOX * BOX;
    float* res_out      = pos_def_out + (size_t)NB * NPTS * 3;
    float* amp_corr_out = res_out + (size_t)NB * NPTS * 3;

    int*   counter = (int*)d_ws;
    float* canvas  = (float*)((char*)d_ws + CANVAS_BYTE_OFF); // [16,264,264]

    // zero counter + canvas in one memset node
    hipMemsetAsync(d_ws, 0,
                   CANVAS_BYTE_OFF + (size_t)CANVAS_ELEMS * sizeof(float),
                   stream);

    mega_kernel<<<NBLK, 256, 0, stream>>>(
        z, r, pos, amp, linamp1_W, ampblock_W, ampblock_b, linamp2_W,
        linamp2_b, lin0_W, deform_W, deform_b, lin1a_W, lin1b_W, k2, dflag,
        counter, canvas, img, pos_def_out, res_out, amp_corr_out);
}

// Round 7
// 151.625 us; speedup vs baseline: 1.3298x; 1.3298x over previous
//
#include <hip/hip_runtime.h>

#define BOX   256
#define KS    9
#define HALF  4
#define NPTS  20000
#define NB    16
#define NLAT  8
#define CANW  264                  // BOX + 2*HALF
#define NPBLK 1250                 // 1250 blocks * 4 waves * 64 pts = 320000
#define CANVAS_ELEMS (NB * CANW * CANW)

typedef _Float16 half8   __attribute__((ext_vector_type(8)));
typedef float    floatx4 __attribute__((ext_vector_type(4)));

// ---------------------------------------------------------------------------
// point kernel: 1 wave = 4 independent groups of 16 points (4x MFMA ILP).
// Weights loaded per layer straight from raw fp32 global with permuted
// addressing (perm_inv(quad*8+j) = quad*4+(j&3) + (j>=4 ? 16 : 0)), converted
// to f16 in-register.  No LDS, no prep kernel.
// ---------------------------------------------------------------------------
__global__ __launch_bounds__(256) void point_kernel(
    const float* __restrict__ z, const float* __restrict__ r,
    const float* __restrict__ pos, const float* __restrict__ amp,
    const float* __restrict__ linamp1_W, const float* __restrict__ ampblock_W,
    const float* __restrict__ ampblock_b, const float* __restrict__ linamp2_W,
    const float* __restrict__ linamp2_b, const float* __restrict__ lin0_W,
    const float* __restrict__ deform_W, const float* __restrict__ deform_b,
    const float* __restrict__ lin1a_W, const float* __restrict__ lin1b_W,
    const int* __restrict__ dflag,
    float* __restrict__ canvas, float* __restrict__ pos_def_out,
    float* __restrict__ res_out, float* __restrict__ amp_corr_out)
{
    const int lane = threadIdx.x & 63;
    const int n    = lane & 15;       // point column AND weight row (tile 0)
    const int quad = lane >> 4;
    const int s    = blockIdx.x * 4 + (threadIdx.x >> 6);   // set id 0..4999
    const int d    = *dflag;
    const float ampv = amp[0];
    const float l2b  = linamp2_b[0];
    const floatx4 zero = {0.f, 0.f, 0.f, 0.f};

    // ---- per-group point data + input fragments ----
    int   bb[4];
    float px[4], py[4], pz[4];
    half8 bfa[4], bfd[4];
    #pragma unroll
    for (int g = 0; g < 4; ++g) {
        const int base_bp = s * 64 + g * 16;
        const int b = base_bp / NPTS;          // groups of 16 never cross batch
        const int p = base_bp - b * NPTS + n;
        bb[g] = b;
        px[g] = pos[3 * p + 0];
        py[g] = pos[3 * p + 1];
        pz[g] = pos[3 * p + 2];
        float zl[NLAT];
        #pragma unroll
        for (int k = 0; k < NLAT; ++k) zl[k] = z[b * NLAT + k];
        half8 t;
        #pragma unroll
        for (int j = 0; j < 8; ++j) t[j] = (_Float16)0.f;
        bfa[g] = t; bfd[g] = t;
        if (quad == 0) {
            bfa[g][0] = (_Float16)px[g]; bfa[g][1] = (_Float16)py[g];
            bfa[g][2] = (_Float16)pz[g]; bfa[g][3] = (_Float16)zl[7];
            bfd[g][0] = (_Float16)px[g]; bfd[g][1] = (_Float16)py[g];
            bfd[g][2] = (_Float16)pz[g]; bfd[g][3] = (_Float16)zl[0];
            bfd[g][4] = (_Float16)zl[1]; bfd[g][5] = (_Float16)zl[2];
            bfd[g][6] = (_Float16)zl[3]; bfd[g][7] = (_Float16)zl[4];
        } else if (quad == 1) {
            bfd[g][0] = (_Float16)zl[5]; bfd[g][1] = (_Float16)zl[6];
        }
    }

    // ========================= amplitude head =========================
    float xB[4][8];
    {
        // linamp1 [32,4]: raw cols (k<4 live, quad 0 only)
        floatx4 w0 = *(const floatx4*)(linamp1_W + n * 4);
        floatx4 w1 = *(const floatx4*)(linamp1_W + (n + 16) * 4);
        half8 a0, a1;
        #pragma unroll
        for (int j = 0; j < 8; ++j) { a0[j] = (_Float16)0.f; a1[j] = (_Float16)0.f; }
        if (quad == 0) {
            #pragma unroll
            for (int j = 0; j < 4; ++j) {
                a0[j] = (_Float16)w0[j];
                a1[j] = (_Float16)w1[j];
            }
        }
        #pragma unroll
        for (int g = 0; g < 4; ++g) {
            floatx4 c0 = __builtin_amdgcn_mfma_f32_16x16x32_f16(a0, bfa[g], zero, 0, 0, 0);
            floatx4 c1 = __builtin_amdgcn_mfma_f32_16x16x32_f16(a1, bfa[g], zero, 0, 0, 0);
            #pragma unroll
            for (int rr = 0; rr < 4; ++rr) { xB[g][rr] = c0[rr]; xB[g][4 + rr] = c1[rr]; }
        }
    }
    #pragma unroll
    for (int l = 0; l < 3; ++l) {
        const float* W = ampblock_W + l * 1024;
        floatx4 f00 = *(const floatx4*)(W + n * 32 + quad * 4);
        floatx4 f01 = *(const floatx4*)(W + n * 32 + 16 + quad * 4);
        floatx4 f10 = *(const floatx4*)(W + (n + 16) * 32 + quad * 4);
        floatx4 f11 = *(const floatx4*)(W + (n + 16) * 32 + 16 + quad * 4);
        half8 a0, a1;
        #pragma unroll
        for (int j = 0; j < 4; ++j) {
            a0[j] = (_Float16)f00[j]; a0[4 + j] = (_Float16)f01[j];
            a1[j] = (_Float16)f10[j]; a1[4 + j] = (_Float16)f11[j];
        }
        floatx4 b0 = *(const floatx4*)(ampblock_b + l * 32 + quad * 4);
        floatx4 b1 = *(const floatx4*)(ampblock_b + l * 32 + 16 + quad * 4);
        #pragma unroll
        for (int g = 0; g < 4; ++g) {
            half8 hf;
            #pragma unroll
            for (int j = 0; j < 8; ++j) hf[j] = (_Float16)xB[g][j];
            floatx4 d0 = __builtin_amdgcn_mfma_f32_16x16x32_f16(a0, hf, zero, 0, 0, 0);
            floatx4 d1 = __builtin_amdgcn_mfma_f32_16x16x32_f16(a1, hf, zero, 0, 0, 0);
            #pragma unroll
            for (int rr = 0; rr < 4; ++rr) {
                xB[g][rr]     += fmaxf(d0[rr] + b0[rr], 0.f);
                xB[g][4 + rr] += fmaxf(d1[rr] + b1[rr], 0.f);
            }
        }
    }
    float corr[4];
    {
        floatx4 wa = *(const floatx4*)(linamp2_W + quad * 4);        // perm cols
        floatx4 wb = *(const floatx4*)(linamp2_W + 16 + quad * 4);
        #pragma unroll
        for (int g = 0; g < 4; ++g) {
            float sd = 0.f;
            #pragma unroll
            for (int rr = 0; rr < 4; ++rr) sd += wa[rr] * xB[g][rr] + wb[rr] * xB[g][4 + rr];
            sd += __shfl_xor(sd, 16);
            sd += __shfl_xor(sd, 32);
            corr[g] = 1.f / (1.f + __expf(-(sd + l2b)));
        }
    }

    // ========================= deformation head =========================
    float r0[4] = {0.f,0.f,0.f,0.f}, r1[4] = {0.f,0.f,0.f,0.f}, r2[4] = {0.f,0.f,0.f,0.f};
    if (d > 0) {
        {
            // lin0 [32,10]: raw cols; quad0 -> cols 0..7, quad1 -> cols 8,9
            float c0v[8], c1v[8];
            #pragma unroll
            for (int j = 0; j < 8; ++j) { c0v[j] = 0.f; c1v[j] = 0.f; }
            const float* row0 = lin0_W + n * 10;
            const float* row1 = lin0_W + (n + 16) * 10;
            if (quad == 0) {
                #pragma unroll
                for (int j = 0; j < 8; ++j) { c0v[j] = row0[j]; c1v[j] = row1[j]; }
            } else if (quad == 1) {
                c0v[0] = row0[8]; c0v[1] = row0[9];
                c1v[0] = row1[8]; c1v[1] = row1[9];
            }
            half8 a0, a1;
            #pragma unroll
            for (int j = 0; j < 8; ++j) {
                a0[j] = (_Float16)c0v[j];
                a1[j] = (_Float16)c1v[j];
            }
            #pragma unroll
            for (int g = 0; g < 4; ++g) {
                floatx4 c0 = __builtin_amdgcn_mfma_f32_16x16x32_f16(a0, bfd[g], zero, 0, 0, 0);
                floatx4 c1 = __builtin_amdgcn_mfma_f32_16x16x32_f16(a1, bfd[g], zero, 0, 0, 0);
                #pragma unroll
                for (int rr = 0; rr < 4; ++rr) { xB[g][rr] = c0[rr]; xB[g][4 + rr] = c1[rr]; }
            }
        }
        #pragma unroll
        for (int l = 0; l < 3; ++l) {
            const float* W = deform_W + l * 1024;
            floatx4 f00 = *(const floatx4*)(W + n * 32 + quad * 4);
            floatx4 f01 = *(const floatx4*)(W + n * 32 + 16 + quad * 4);
            floatx4 f10 = *(const floatx4*)(W + (n + 16) * 32 + quad * 4);
            floatx4 f11 = *(const floatx4*)(W + (n + 16) * 32 + 16 + quad * 4);
            half8 a0, a1;
            #pragma unroll
            for (int j = 0; j < 4; ++j) {
                a0[j] = (_Float16)f00[j]; a0[4 + j] = (_Float16)f01[j];
                a1[j] = (_Float16)f10[j]; a1[4 + j] = (_Float16)f11[j];
            }
            floatx4 b0 = *(const floatx4*)(deform_b + l * 32 + quad * 4);
            floatx4 b1 = *(const floatx4*)(deform_b + l * 32 + 16 + quad * 4);
            #pragma unroll
            for (int g = 0; g < 4; ++g) {
                half8 hf;
                #pragma unroll
                for (int j = 0; j < 8; ++j) hf[j] = (_Float16)xB[g][j];
                floatx4 d0 = __builtin_amdgcn_mfma_f32_16x16x32_f16(a0, hf, zero, 0, 0, 0);
                floatx4 d1 = __builtin_amdgcn_mfma_f32_16x16x32_f16(a1, hf, zero, 0, 0, 0);
                #pragma unroll
                for (int rr = 0; rr < 4; ++rr) {
                    xB[g][rr]     += fmaxf(d0[rr] + b0[rr], 0.f);
                    xB[g][4 + rr] += fmaxf(d1[rr] + b1[rr], 0.f);
                }
            }
        }
        // tail: t3_i = tanh(x . lin1a_i), then lin1b
        #pragma unroll
        for (int i = 0; i < 3; ++i) {
            floatx4 wa = *(const floatx4*)(lin1a_W + i * 32 + quad * 4);
            floatx4 wb = *(const floatx4*)(lin1a_W + i * 32 + 16 + quad * 4);
            const float lb0 = lin1b_W[0 * 3 + i];
            const float lb1 = lin1b_W[1 * 3 + i];
            const float lb2 = lin1b_W[2 * 3 + i];
            #pragma unroll
            for (int g = 0; g < 4; ++g) {
                float sd = 0.f;
                #pragma unroll
                for (int rr = 0; rr < 4; ++rr) sd += wa[rr] * xB[g][rr] + wb[rr] * xB[g][4 + rr];
                sd += __shfl_xor(sd, 16);
                sd += __shfl_xor(sd, 32);
                const float t3 = 1.f - 2.f / (__expf(2.f * sd) + 1.f);
                r0[g] = fmaf(t3, lb0, r0[g]);
                r1[g] = fmaf(t3, lb1, r1[g]);
                r2[g] = fmaf(t3, lb2, r2[g]);
            }
        }
    }

    // ---- outputs (quad-split; every quad holds full replicated results) ----
    #pragma unroll
    for (int g = 0; g < 4; ++g) {
        const int bp = s * 64 + g * 16 + n;
        const float pdx = px[g] + r0[g], pdy = py[g] + r1[g], pdz = pz[g] + r2[g];
        if (quad == 0) {
            pos_def_out[3 * bp + 0] = pdx;
            pos_def_out[3 * bp + 1] = pdy;
            pos_def_out[3 * bp + 2] = pdz;
        } else if (quad == 1) {
            res_out[3 * bp + 0] = r0[g];
            res_out[3 * bp + 1] = r1[g];
            res_out[3 * bp + 2] = r2[g];
        } else if (quad == 2) {
            amp_corr_out[bp] = corr[g];
        } else {
            const float* rb = r + bb[g] * 9;
            const float pjx = rb[0] * pdx + rb[1] * pdy + rb[2] * pdz;
            const float pjy = rb[3] * pdx + rb[4] * pdy + rb[5] * pdz;
            const int cx = (int)rintf((pjx + 0.5f) * (float)(BOX - 1));
            const int cy = (int)rintf((pjy + 0.5f) * (float)(BOX - 1));
            if (cx >= -HALF && cx <= BOX - 1 + HALF &&
                cy >= -HALF && cy <= BOX - 1 + HALF) {
                atomicAdd(canvas + ((size_t)bb[g] * CANW + (cy + HALF)) * CANW + (cx + HALF),
                          ampv * corr[g]);
            }
        }
    }
}

// ---------------------------------------------------------------------------
// fused separable conv: one block per (b, 16-row stripe).  g computed from k2.
// ---------------------------------------------------------------------------
__global__ __launch_bounds__(256) void conv_kernel(
    const float* __restrict__ canvas, const float* __restrict__ k2,
    float* __restrict__ img)
{
    __shared__ float t_lds[24][256];
    const int x  = threadIdx.x;
    const int b  = blockIdx.x >> 4;
    const int y0 = (blockIdx.x & 15) * 16;

    float g[KS];
    #pragma unroll
    for (int i = 0; i < KS; ++i) {
        float sg = 0.f;
        #pragma unroll
        for (int j = 0; j < KS; ++j) sg += k2[i * KS + j];
        g[i] = sg;
    }

    const float* cb = canvas + (size_t)b * CANW * CANW;
    #pragma unroll 4
    for (int rr = 0; rr < 24; ++rr) {
        const float* row = cb + (size_t)(y0 + rr) * CANW;
        float s = 0.f;
        #pragma unroll
        for (int i = 0; i < KS; ++i) s = fmaf(g[i], row[x + (KS - 1) - i], s);
        t_lds[rr][x] = s;
    }
    __syncthreads();

    float* ib = img + ((size_t)b * BOX + y0) * BOX;
    #pragma unroll 4
    for (int yy = 0; yy < 16; ++yy) {
        float s = 0.f;
        #pragma unroll
        for (int i = 0; i < KS; ++i) s = fmaf(g[i], t_lds[yy + (KS - 1) - i][x], s);
        ib[yy * BOX + x] = s;
    }
}

extern "C" void kernel_launch(void* const* d_in, const int* in_sizes, int n_in,
                              void* d_out, int out_size, void* d_ws, size_t ws_size,
                              hipStream_t stream) {
    const float* z          = (const float*)d_in[0];
    const float* r          = (const float*)d_in[1];
    const float* pos        = (const float*)d_in[2];
    const float* amp        = (const float*)d_in[3];
    const float* linamp1_W  = (const float*)d_in[4];
    const float* ampblock_W = (const float*)d_in[5];
    const float* ampblock_b = (const float*)d_in[6];
    const float* linamp2_W  = (const float*)d_in[7];
    const float* linamp2_b  = (const float*)d_in[8];
    const float* lin0_W     = (const float*)d_in[9];
    const float* deform_W   = (const float*)d_in[10];
    const float* deform_b   = (const float*)d_in[11];
    const float* lin1a_W    = (const float*)d_in[12];
    const float* lin1b_W    = (const float*)d_in[13];
    const float* k2         = (const float*)d_in[14];
    const int*   dflag      = (const int*)d_in[15];

    float* out = (float*)d_out;
    float* img          = out;                               // [16,256,256]
    float* pos_def_out  = out + (size_t)NB * BOX * BOX;
    float* res_out      = pos_def_out + (size_t)NB * NPTS * 3;
    float* amp_corr_out = res_out + (size_t)NB * NPTS * 3;

    float* canvas = (float*)d_ws;                            // [16,264,264]

    hipMemsetAsync(canvas, 0, (size_t)CANVAS_ELEMS * sizeof(float), stream);

    point_kernel<<<NPBLK, 256, 0, stream>>>(
        z, r, pos, amp, linamp1_W, ampblock_W, ampblock_b, linamp2_W,
        linamp2_b, lin0_W, deform_W, deform_b, lin1a_W, lin1b_W, dflag,
        canvas, pos_def_out, res_out, amp_corr_out);

    conv_kernel<<<NB * 16, 256, 0, stream>>>(canvas, k2, img);
}

// Round 9
// 136.545 us; speedup vs baseline: 1.4767x; 1.1104x over previous
//
#include <hip/hip_runtime.h>

#define BOX   256
#define KS    9
#define HALF  4
#define NPTS  20000
#define NB    16
#define NLAT  8
#define CANW  264                  // BOX + 2*HALF
#define NPBLK 2500                 // 4 waves/block * 2 groups * 16 pts = 128 pts/block
#define CANVAS_ELEMS (NB * CANW * CANW)

typedef _Float16 half8   __attribute__((ext_vector_type(8)));
typedef __fp16   fp16x2  __attribute__((ext_vector_type(2)));
typedef float    floatx4 __attribute__((ext_vector_type(4)));

// ws layout: [0,16384) 8 f16 weight mats [32][32] (A-operand form)
//            [16384,...) canvas [16][264][264] fp32
#define WH_BYTES 16384

// B-slot k holds neuron perm_inv(k); hidden-layer weight cols permuted to match.
__device__ __forceinline__ int perm_inv(int k) {
    return ((k >> 2) & 1) * 16 + (k >> 3) * 4 + (k & 3);
}

// fp32[8] -> half8 via packed RTZ converts (4 VALU insts)
__device__ __forceinline__ half8 pack8(const float x[8]) {
    union { fp16x2 v2[4]; half8 v8; } u;
    u.v2[0] = __builtin_amdgcn_cvt_pkrtz(x[0], x[1]);
    u.v2[1] = __builtin_amdgcn_cvt_pkrtz(x[2], x[3]);
    u.v2[2] = __builtin_amdgcn_cvt_pkrtz(x[4], x[5]);
    u.v2[3] = __builtin_amdgcn_cvt_pkrtz(x[6], x[7]);
    return u.v8;
}

// ---------------------------------------------------------------------------
// prep: build 8 padded [32][32] f16 A-operand matrices.
//  0: linamp1 (raw cols, k<4)   1..3: ampblock (perm cols)
//  4: lin0    (raw cols, k<10)  5..7: deform  (perm cols)
// ---------------------------------------------------------------------------
__global__ __launch_bounds__(256) void prep_kernel(
    const float* __restrict__ linamp1_W, const float* __restrict__ ampblock_W,
    const float* __restrict__ lin0_W, const float* __restrict__ deform_W,
    _Float16* __restrict__ wh)
{
    const int idx = blockIdx.x * 256 + threadIdx.x;
    if (idx >= 8192) return;
    const int mat = idx >> 10, rem = idx & 1023;
    const int m = rem >> 5, k = rem & 31;
    float v = 0.0f;
    if (mat == 0)      { if (k < 4)  v = linamp1_W[m * 4 + k]; }
    else if (mat <= 3) { v = ampblock_W[(mat - 1) * 1024 + m * 32 + perm_inv(k)]; }
    else if (mat == 4) { if (k < 10) v = lin0_W[m * 10 + k]; }
    else               { v = deform_W[(mat - 5) * 1024 + m * 32 + perm_inv(k)]; }
    wh[idx] = (_Float16)v;
}

// ---------------------------------------------------------------------------
// point kernel: 1 wave = 2 groups of 16 points.  Bias folded into MFMA C.
// ---------------------------------------------------------------------------
__global__ __launch_bounds__(256) void point_kernel(
    const float* __restrict__ z, const float* __restrict__ r,
    const float* __restrict__ pos, const float* __restrict__ amp,
    const float* __restrict__ ampblock_b, const float* __restrict__ linamp2_W,
    const float* __restrict__ linamp2_b, const float* __restrict__ deform_b,
    const float* __restrict__ lin1a_W, const float* __restrict__ lin1b_W,
    const int* __restrict__ dflag, const _Float16* __restrict__ wh,
    float* __restrict__ canvas, float* __restrict__ pos_def_out,
    float* __restrict__ res_out, float* __restrict__ amp_corr_out)
{
    const int lane = threadIdx.x & 63;
    const int n    = lane & 15;
    const int quad = lane >> 4;
    const int aoff = quad * 8;
    const int s    = blockIdx.x * 4 + (threadIdx.x >> 6);   // set id 0..9999
    const int d    = *dflag;
    const float ampv = amp[0];
    const float l2b  = linamp2_b[0];
    const floatx4 zero = {0.f, 0.f, 0.f, 0.f};

    const int base0 = s * 32;            // 625 sets per batch: never crosses
    const int b     = base0 / NPTS;

    float zl[NLAT];
    #pragma unroll
    for (int k = 0; k < NLAT; ++k) zl[k] = z[b * NLAT + k];

    float px[2], py[2], pz[2];
    half8 bfa[2], bfd[2];
    #pragma unroll
    for (int g = 0; g < 2; ++g) {
        const int p = base0 - b * NPTS + g * 16 + n;
        px[g] = pos[3 * p + 0];
        py[g] = pos[3 * p + 1];
        pz[g] = pos[3 * p + 2];
        half8 t;
        #pragma unroll
        for (int j = 0; j < 8; ++j) t[j] = (_Float16)0.f;
        bfa[g] = t; bfd[g] = t;
        if (quad == 0) {
            bfa[g][0] = (_Float16)px[g]; bfa[g][1] = (_Float16)py[g];
            bfa[g][2] = (_Float16)pz[g]; bfa[g][3] = (_Float16)zl[7];
            bfd[g][0] = (_Float16)px[g]; bfd[g][1] = (_Float16)py[g];
            bfd[g][2] = (_Float16)pz[g]; bfd[g][3] = (_Float16)zl[0];
            bfd[g][4] = (_Float16)zl[1]; bfd[g][5] = (_Float16)zl[2];
            bfd[g][6] = (_Float16)zl[3]; bfd[g][7] = (_Float16)zl[4];
        } else if (quad == 1) {
            bfd[g][0] = (_Float16)zl[5]; bfd[g][1] = (_Float16)zl[6];
        }
    }

    // ========================= amplitude head =========================
    float xB[2][8];
    {
        half8 a0 = *(const half8*)(wh + n * 32 + aoff);
        half8 a1 = *(const half8*)(wh + (n + 16) * 32 + aoff);
        #pragma unroll
        for (int g = 0; g < 2; ++g) {
            floatx4 c0 = __builtin_amdgcn_mfma_f32_16x16x32_f16(a0, bfa[g], zero, 0, 0, 0);
            floatx4 c1 = __builtin_amdgcn_mfma_f32_16x16x32_f16(a1, bfa[g], zero, 0, 0, 0);
            #pragma unroll
            for (int rr = 0; rr < 4; ++rr) { xB[g][rr] = c0[rr]; xB[g][4 + rr] = c1[rr]; }
        }
    }
    #pragma unroll
    for (int l = 0; l < 3; ++l) {
        const _Float16* M = wh + (1 + l) * 1024;
        half8 a0 = *(const half8*)(M + n * 32 + aoff);
        half8 a1 = *(const half8*)(M + (n + 16) * 32 + aoff);
        floatx4 b0 = *(const floatx4*)(ampblock_b + l * 32 + quad * 4);
        floatx4 b1 = *(const floatx4*)(ampblock_b + l * 32 + 16 + quad * 4);
        #pragma unroll
        for (int g = 0; g < 2; ++g) {
            half8 hf = pack8(xB[g]);
            floatx4 d0 = __builtin_amdgcn_mfma_f32_16x16x32_f16(a0, hf, b0, 0, 0, 0);
            floatx4 d1 = __builtin_amdgcn_mfma_f32_16x16x32_f16(a1, hf, b1, 0, 0, 0);
            #pragma unroll
            for (int rr = 0; rr < 4; ++rr) {
                xB[g][rr]     += fmaxf(d0[rr], 0.f);
                xB[g][4 + rr] += fmaxf(d1[rr], 0.f);
            }
        }
    }
    float corr[2];
    {
        floatx4 wa = *(const floatx4*)(linamp2_W + quad * 4);
        floatx4 wb = *(const floatx4*)(linamp2_W + 16 + quad * 4);
        #pragma unroll
        for (int g = 0; g < 2; ++g) {
            float sd = 0.f;
            #pragma unroll
            for (int rr = 0; rr < 4; ++rr) sd += wa[rr] * xB[g][rr] + wb[rr] * xB[g][4 + rr];
            sd += __shfl_xor(sd, 16);
            sd += __shfl_xor(sd, 32);
            corr[g] = 1.f / (1.f + __expf(-(sd + l2b)));
        }
    }

    // ========================= deformation head =========================
    float r0[2] = {0.f, 0.f}, r1[2] = {0.f, 0.f}, r2[2] = {0.f, 0.f};
    if (d > 0) {
        {
            const _Float16* M = wh + 4 * 1024;
            half8 a0 = *(const half8*)(M + n * 32 + aoff);
            half8 a1 = *(const half8*)(M + (n + 16) * 32 + aoff);
            #pragma unroll
            for (int g = 0; g < 2; ++g) {
                floatx4 c0 = __builtin_amdgcn_mfma_f32_16x16x32_f16(a0, bfd[g], zero, 0, 0, 0);
                floatx4 c1 = __builtin_amdgcn_mfma_f32_16x16x32_f16(a1, bfd[g], zero, 0, 0, 0);
                #pragma unroll
                for (int rr = 0; rr < 4; ++rr) { xB[g][rr] = c0[rr]; xB[g][4 + rr] = c1[rr]; }
            }
        }
        #pragma unroll
        for (int l = 0; l < 3; ++l) {
            const _Float16* M = wh + (5 + l) * 1024;
            half8 a0 = *(const half8*)(M + n * 32 + aoff);
            half8 a1 = *(const half8*)(M + (n + 16) * 32 + aoff);
            floatx4 b0 = *(const floatx4*)(deform_b + l * 32 + quad * 4);
            floatx4 b1 = *(const floatx4*)(deform_b + l * 32 + 16 + quad * 4);
            #pragma unroll
            for (int g = 0; g < 2; ++g) {
                half8 hf = pack8(xB[g]);
                floatx4 d0 = __builtin_amdgcn_mfma_f32_16x16x32_f16(a0, hf, b0, 0, 0, 0);
                floatx4 d1 = __builtin_amdgcn_mfma_f32_16x16x32_f16(a1, hf, b1, 0, 0, 0);
                #pragma unroll
                for (int rr = 0; rr < 4; ++rr) {
                    xB[g][rr]     += fmaxf(d0[rr], 0.f);
                    xB[g][4 + rr] += fmaxf(d1[rr], 0.f);
                }
            }
        }
        #pragma unroll
        for (int i = 0; i < 3; ++i) {
            floatx4 wa = *(const floatx4*)(lin1a_W + i * 32 + quad * 4);
            floatx4 wb = *(const floatx4*)(lin1a_W + i * 32 + 16 + quad * 4);
            const float lb0 = lin1b_W[0 * 3 + i];
            const float lb1 = lin1b_W[1 * 3 + i];
            const float lb2 = lin1b_W[2 * 3 + i];
            #pragma unroll
            for (int g = 0; g < 2; ++g) {
                float sd = 0.f;
                #pragma unroll
                for (int rr = 0; rr < 4; ++rr) sd += wa[rr] * xB[g][rr] + wb[rr] * xB[g][4 + rr];
                sd += __shfl_xor(sd, 16);
                sd += __shfl_xor(sd, 32);
                const float t3 = 1.f - 2.f / (__expf(2.f * sd) + 1.f);
                r0[g] = fmaf(t3, lb0, r0[g]);
                r1[g] = fmaf(t3, lb1, r1[g]);
                r2[g] = fmaf(t3, lb2, r2[g]);
            }
        }
    }

    // ---- outputs (quad-split; every quad holds full replicated results) ----
    #pragma unroll
    for (int g = 0; g < 2; ++g) {
        const int bp = base0 + g * 16 + n;
        const float pdx = px[g] + r0[g], pdy = py[g] + r1[g], pdz = pz[g] + r2[g];
        if (quad == 0) {
            pos_def_out[3 * bp + 0] = pdx;
            pos_def_out[3 * bp + 1] = pdy;
            pos_def_out[3 * bp + 2] = pdz;
        } else if (quad == 1) {
            res_out[3 * bp + 0] = r0[g];
            res_out[3 * bp + 1] = r1[g];
            res_out[3 * bp + 2] = r2[g];
        } else if (quad == 2) {
            amp_corr_out[bp] = corr[g];
        } else {
            const float* rb = r + b * 9;
            const float pjx = rb[0] * pdx + rb[1] * pdy + rb[2] * pdz;
            const float pjy = rb[3] * pdx + rb[4] * pdy + rb[5] * pdz;
            const int cx = (int)rintf((pjx + 0.5f) * (float)(BOX - 1));
            const int cy = (int)rintf((pjy + 0.5f) * (float)(BOX - 1));
            if (cx >= -HALF && cx <= BOX - 1 + HALF &&
                cy >= -HALF && cy <= BOX - 1 + HALF) {
                atomicAdd(canvas + ((size_t)b * CANW + (cy + HALF)) * CANW + (cx + HALF),
                          ampv * corr[g]);
            }
        }
    }
}

// ---------------------------------------------------------------------------
// fused separable conv: one block per (b, 16-row stripe).
// ---------------------------------------------------------------------------
__global__ __launch_bounds__(256) void conv_kernel(
    const float* __restrict__ canvas, const float* __restrict__ k2,
    float* __restrict__ img)
{
    __shared__ float t_lds[24][256];
    const int x  = threadIdx.x;
    const int b  = blockIdx.x >> 4;
    const int y0 = (blockIdx.x & 15) * 16;

    float g[KS];
    #pragma unroll
    for (int i = 0; i < KS; ++i) {
        float sg = 0.f;
        #pragma unroll
        for (int j = 0; j < KS; ++j) sg += k2[i * KS + j];
        g[i] = sg;
    }

    const float* cb = canvas + (size_t)b * CANW * CANW;
    #pragma unroll 4
    for (int rr = 0; rr < 24; ++rr) {
        const float* row = cb + (size_t)(y0 + rr) * CANW;
        float s = 0.f;
        #pragma unroll
        for (int i = 0; i < KS; ++i) s = fmaf(g[i], row[x + (KS - 1) - i], s);
        t_lds[rr][x] = s;
    }
    __syncthreads();

    float* ib = img + ((size_t)b * BOX + y0) * BOX;
    #pragma unroll 4
    for (int yy = 0; yy < 16; ++yy) {
        float s = 0.f;
        #pragma unroll
        for (int i = 0; i < KS; ++i) s = fmaf(g[i], t_lds[yy + (KS - 1) - i][x], s);
        ib[yy * BOX + x] = s;
    }
}

extern "C" void kernel_launch(void* const* d_in, const int* in_sizes, int n_in,
                              void* d_out, int out_size, void* d_ws, size_t ws_size,
                              hipStream_t stream) {
    const float* z          = (const float*)d_in[0];
    const float* r          = (const float*)d_in[1];
    const float* pos        = (const float*)d_in[2];
    const float* amp        = (const float*)d_in[3];
    const float* linamp1_W  = (const float*)d_in[4];
    const float* ampblock_W = (const float*)d_in[5];
    const float* ampblock_b = (const float*)d_in[6];
    const float* linamp2_W  = (const float*)d_in[7];
    const float* linamp2_b  = (const float*)d_in[8];
    const float* lin0_W     = (const float*)d_in[9];
    const float* deform_W   = (const float*)d_in[10];
    const float* deform_b   = (const float*)d_in[11];
    const float* lin1a_W    = (const float*)d_in[12];
    const float* lin1b_W    = (const float*)d_in[13];
    const float* k2         = (const float*)d_in[14];
    const int*   dflag      = (const int*)d_in[15];

    float* out = (float*)d_out;
    float* img          = out;                               // [16,256,256]
    float* pos_def_out  = out + (size_t)NB * BOX * BOX;
    float* res_out      = pos_def_out + (size_t)NB * NPTS * 3;
    float* amp_corr_out = res_out + (size_t)NB * NPTS * 3;

    _Float16* wh     = (_Float16*)d_ws;
    float*    canvas = (float*)((char*)d_ws + WH_BYTES);     // [16,264,264]

    (void)hipMemsetAsync(canvas, 0, (size_t)CANVAS_ELEMS * sizeof(float), stream);

    prep_kernel<<<32, 256, 0, stream>>>(
        linamp1_W, ampblock_W, lin0_W, deform_W, wh);

    point_kernel<<<NPBLK, 256, 0, stream>>>(
        z, r, pos, amp, ampblock_b, linamp2_W, linamp2_b, deform_b,
        lin1a_W, lin1b_W, dflag, wh, canvas,
        pos_def_out, res_out, amp_corr_out);

    conv_kernel<<<NB * 16, 256, 0, stream>>>(canvas, k2, img);
}